// Round 3
// baseline (181.957 us; speedup 1.0000x reference)
//
#include <hip/hip_runtime.h>
#include <hip/hip_bf16.h>
#include <math.h>

typedef unsigned short u16;
typedef unsigned int u32;
typedef __attribute__((ext_vector_type(8))) short short8v;   // 8 bf16 = 4 VGPR
typedef __attribute__((ext_vector_type(4))) float f32x4;
typedef __attribute__((ext_vector_type(16))) float f32x16;

#define BB 2
#define TT 2048
#define DD 768
#define HH 12
#define DHH 64
#define MM 4096   // BB*TT

// XOR swizzle for row-major [r][128B] LDS tiles (read side).
#define SWZ(r, kb) (((r) * 128) + ((kb) ^ (((r) & 7) << 4)))

// global -> LDS direct copy, 16B per lane, dest = wave-uniform base + lane*16
typedef __attribute__((address_space(1))) void gas_void;
typedef __attribute__((address_space(3))) void las_void;
#define GLL(g, l) __builtin_amdgcn_global_load_lds((gas_void*)(g), (las_void*)(l), 16, 0, 0)

__device__ __forceinline__ u16 f2bf(float f) {
    union { float f; unsigned u; } v; v.f = f;
    unsigned r = v.u + 0x7fff + ((v.u >> 16) & 1);   // RNE
    return (u16)(r >> 16);
}
__device__ __forceinline__ u32 pkpair(float a, float b) {   // low=a, high=b
    union { __hip_bfloat162 h; u32 u; } v;
    v.h = __float22bfloat162_rn(make_float2(a, b));
    return v.u;
}

// ---------------------------------------------------------------------------
// x fp32 -> bf16 row-major. grid 3072 x 256, one float4/thread.
// ---------------------------------------------------------------------------
__global__ __launch_bounds__(256) void convert_x(const float* __restrict__ x,
                                                 u16* __restrict__ xb) {
    const int i = blockIdx.x * 256 + threadIdx.x;
    const float4 v = ((const float4*)x)[i];
    union { u16 s[4]; uint2 u; } o;
    o.s[0] = f2bf(v.x); o.s[1] = f2bf(v.y); o.s[2] = f2bf(v.z); o.s[3] = f2bf(v.w);
    ((uint2*)xb)[i] = o.u;
}

// ---------------------------------------------------------------------------
// W [K][N] fp32 -> Wt [N][K] bf16. grid (12,12,4).
// ---------------------------------------------------------------------------
__global__ __launch_bounds__(256) void transpose_cvt(
    const float* __restrict__ W0, const float* __restrict__ W1,
    const float* __restrict__ W2, const float* __restrict__ W3,
    u16* __restrict__ T0, u16* __restrict__ T1,
    u16* __restrict__ T2, u16* __restrict__ T3)
{
    const int z = blockIdx.z;
    const float* __restrict__ W = (z == 0) ? W0 : (z == 1) ? W1 : (z == 2) ? W2 : W3;
    u16* __restrict__ T = (z == 0) ? T0 : (z == 1) ? T1 : (z == 2) ? T2 : T3;

    __shared__ float tile[64][65];
    const int k0 = blockIdx.x * 64, n0 = blockIdx.y * 64;
    const int t = threadIdx.x;
    const int rr = t >> 4, c4 = (t & 15) * 4;

    #pragma unroll
    for (int j = 0; j < 4; ++j) {
        const int r = rr + j * 16;
        const float4 v = *(const float4*)&W[(size_t)(k0 + r) * DD + n0 + c4];
        tile[r][c4 + 0] = v.x; tile[r][c4 + 1] = v.y;
        tile[r][c4 + 2] = v.z; tile[r][c4 + 3] = v.w;
    }
    __syncthreads();
    #pragma unroll
    for (int j = 0; j < 4; ++j) {
        const int r = rr + j * 16;
        union { u16 s[4]; uint2 u; } o;
        #pragma unroll
        for (int jj = 0; jj < 4; ++jj) o.s[jj] = f2bf(tile[c4 + jj][r]);
        *(uint2*)&T[(size_t)(n0 + r) * DD + k0 + c4] = o.u;
    }
}

// ---------------------------------------------------------------------------
// bf16 MFMA GEMM, B^T input. 128x128 tile, BK=64, 4 waves (2x2).
// Staging via global_load_lds (linear dest + inverse-swizzled source),
// reads swizzled (rule #21). Modes as round 2.
// ---------------------------------------------------------------------------
__global__ __launch_bounds__(256) void gemm_bt(
    const u16* __restrict__ A,
    const u16* __restrict__ Bt0, const u16* __restrict__ Bt1, const u16* __restrict__ Bt2,
    const float* __restrict__ b0, const float* __restrict__ b1, const float* __restrict__ b2,
    u16* __restrict__ oQ, u16* __restrict__ oK, u16* __restrict__ oVt,
    float* __restrict__ oF, int mode_base)
{
    const int mode = mode_base + blockIdx.z;
    const u16* __restrict__ Bt = (mode == 1) ? Bt1 : (mode == 2) ? Bt2 : Bt0;
    const float* __restrict__ bias = (mode == 1) ? b1 : (mode == 2) ? b2 : b0;

    __shared__ __attribute__((aligned(16))) u16 As[128 * 64];
    __shared__ __attribute__((aligned(16))) u16 Bs[128 * 64];

    const int tid = threadIdx.x, lane = tid & 63, w = tid >> 6;
    const int wr = w >> 1, wc = w & 1;
    const int lr = lane >> 4, lc = lane & 15;
    const int m0 = blockIdx.x * 128, n0 = blockIdx.y * 128;
    const int srcoff = 16 * ((lane & 7) ^ (lane >> 3));   // inverse swizzle (r&7 == lane>>3)

    f32x4 acc[4][4];
    #pragma unroll
    for (int m = 0; m < 4; ++m)
        #pragma unroll
        for (int n = 0; n < 4; ++n) acc[m][n] = (f32x4){0.f, 0.f, 0.f, 0.f};

    #pragma unroll 1
    for (int k0 = 0; k0 < DD; k0 += 64) {
        __syncthreads();
        #pragma unroll
        for (int i = 0; i < 4; ++i) {
            const int r = w * 32 + i * 8 + (lane >> 3);
            GLL((const char*)A  + ((size_t)(m0 + r) * DD + k0) * 2 + srcoff,
                (char*)As + w * 4096 + i * 1024);
            GLL((const char*)Bt + ((size_t)(n0 + r) * DD + k0) * 2 + srcoff,
                (char*)Bs + w * 4096 + i * 1024);
        }
        __syncthreads();   // drains vmcnt -> staged data visible
        #pragma unroll
        for (int s = 0; s < 2; ++s) {
            short8v af[4], bf[4];
            #pragma unroll
            for (int m = 0; m < 4; ++m)
                af[m] = *(const short8v*)((const char*)As +
                         SWZ(wr * 64 + m * 16 + lc, s * 64 + lr * 16));
            #pragma unroll
            for (int n = 0; n < 4; ++n)
                bf[n] = *(const short8v*)((const char*)Bs +
                         SWZ(wc * 64 + n * 16 + lc, s * 64 + lr * 16));
            #pragma unroll
            for (int m = 0; m < 4; ++m)
                #pragma unroll
                for (int n = 0; n < 4; ++n)
                    acc[m][n] = __builtin_amdgcn_mfma_f32_16x16x32_bf16(
                        af[m], bf[n], acc[m][n], 0, 0, 0);
        }
    }

    #pragma unroll
    for (int n = 0; n < 4; ++n) {
        const int ng = n0 + wc * 64 + n * 16 + lc;
        const float bv = bias[ng];
        #pragma unroll
        for (int m = 0; m < 4; ++m) {
            const int mg0 = m0 + wr * 64 + m * 16 + lr * 4;
            if (mode == 3) {
                #pragma unroll
                for (int r = 0; r < 4; ++r)
                    oF[(size_t)(mg0 + r) * DD + ng] = acc[m][n][r] + bv;
            } else if (mode == 2) {
                const int bb = mg0 >> 11, tp = mg0 & 2047;
                const int h = ng >> 6, d = ng & 63;
                union { u16 s[4]; uint2 u; } o;
                #pragma unroll
                for (int r = 0; r < 4; ++r) o.s[r] = f2bf(acc[m][n][r] + bv);
                *(uint2*)&oVt[((size_t)(bb * HH + h) * DHH + d) * TT + tp] = o.u;
            } else {
                u16* __restrict__ dst = (mode == 0) ? oQ : oK;
                #pragma unroll
                for (int r = 0; r < 4; ++r) {
                    const int mg = mg0 + r;
                    const int bb = mg >> 11, tp = mg & 2047;
                    const int h = ng >> 6, d = ng & 63;
                    dst[((size_t)(bb * HH + h) * TT + tp) * DHH + d] =
                        f2bf(acc[m][n][r] + bv);
                }
            }
        }
    }
}

// ---------------------------------------------------------------------------
// MFMA flash attention, causal, 32x32x16, swapped QK^T.
// 2 waves/block (128 thr), wave owns 32 q-rows; KVBLK=64, K/V double-buffered
// in LDS via global_load_lds (pre-swizzled source). One barrier per tile.
// grid = 768 1-D: bid = (31-qt)*24 + bh  -> global LPT + bh->XCD affinity.
//
// Layouts (all verified against round-2-proven 16x16 mappings / guide m74):
//  S^T = mfma32(A=K, B=Q): lane holds P^T[k][q], q = lane&31,
//        k = kf*32 + (reg&3) + 8*(reg>>2) + 4*hi       (hi = lane>>5)
//  PV A-frag af[ka] elem e: P[q=lane&31][k = ka*16 + hi*8 + e]
//   -> word j of af[ka]: self-half uses regs rbS=4*((ka&1)*2+hi)+{0..3} of
//      kf=ka>>1; partner-half (shfl_xor 32) uses rbO=4*((ka&1)*2+(hi^1)).
//  accO[dc] (f32x16): q_row = (reg&3)+8*(reg>>2)+4*hi, d = dc*32 + (lane&31)
// ---------------------------------------------------------------------------
__global__ __launch_bounds__(128) void attn_fwd(
    const u16* __restrict__ qb, const u16* __restrict__ kbf,
    const u16* __restrict__ vtb, u16* __restrict__ ctx)
{
    __shared__ __attribute__((aligned(16))) unsigned char smem[32768];
    // K: buf0 @0, buf1 @8192 ; V: buf0 @16384, buf1 @24576

    const int bid = blockIdx.x;
    const int qt = 31 - (bid / 24);
    const int bh = bid - (bid / 24) * 24;
    const int b = bh / HH, h = bh - b * HH;
    const int tid = threadIdx.x, lane = tid & 63, w = tid >> 6;
    const int l31 = lane & 31, hi = lane >> 5;
    const int srcoff = 16 * ((lane & 7) ^ (lane >> 3));

    // Q fragments straight from global: Q[q = qt*64 + w*32 + l31][d = s*16+hi*8 ..+7]
    short8v aq[4];
    {
        const u16* qrow = qb + ((size_t)bh * TT + qt * 64 + w * 32 + l31) * DHH;
        #pragma unroll
        for (int s = 0; s < 4; ++s)
            aq[s] = *(const short8v*)(qrow + s * 16 + hi * 8);
    }

    const char* kbase0 = (const char*)kbf + ((size_t)bh * TT) * (DHH * 2);
    const char* vbase0 = (const char*)vtb + ((size_t)bh * DHH) * (TT * 2);

    // stage tile kt2 into buffer bufi (each wave stages its 32 rows of K and V)
#define STAGE(kt2, bufi) do {                                                   \
        const char* kb_ = kbase0 + (size_t)(kt2) * 64 * 128;                    \
        const char* vb_ = vbase0 + (size_t)(kt2) * 128;                         \
        _Pragma("unroll")                                                       \
        for (int i_ = 0; i_ < 4; ++i_) {                                        \
            const int r_ = w * 32 + i_ * 8 + (lane >> 3);                       \
            GLL(kb_ + (size_t)r_ * 128 + srcoff,                                \
                (char*)smem + (bufi) * 8192 + w * 4096 + i_ * 1024);            \
            GLL(vb_ + (size_t)r_ * (TT * 2) + srcoff,                           \
                (char*)smem + 16384 + (bufi) * 8192 + w * 4096 + i_ * 1024);    \
        }                                                                       \
    } while (0)

    f32x16 accO[2];
    #pragma unroll
    for (int i = 0; i < 16; ++i) { accO[0][i] = 0.f; accO[1][i] = 0.f; }
    float mreg = -INFINITY, lreg = 0.f;

    STAGE(0, 0);
    __syncthreads();

    int cur = 0;
    #pragma unroll 1
    for (int kt = 0; kt <= qt; ++kt) {
        if (kt < qt) STAGE(kt + 1, cur ^ 1);

        const unsigned char* Kb = smem + cur * 8192;
        const unsigned char* Vb = smem + 16384 + cur * 8192;

        // S^T = K * Q^T   (raw scores; scale folded into exp)
        f32x16 st[2];
        #pragma unroll
        for (int i = 0; i < 16; ++i) { st[0][i] = 0.f; st[1][i] = 0.f; }
        #pragma unroll
        for (int s = 0; s < 4; ++s) {
            #pragma unroll
            for (int kf = 0; kf < 2; ++kf) {
                const short8v ak = *(const short8v*)(Kb +
                    SWZ(kf * 32 + l31, s * 32 + hi * 16));
                st[kf] = __builtin_amdgcn_mfma_f32_32x32x16_bf16(ak, aq[s], st[kf], 0, 0, 0);
            }
        }

        if (kt == qt) {   // causal mask on the diagonal tile
            const int qloc = w * 32 + l31;
            #pragma unroll
            for (int kf = 0; kf < 2; ++kf)
                #pragma unroll
                for (int reg = 0; reg < 16; ++reg) {
                    const int kloc = kf * 32 + (reg & 3) + 8 * (reg >> 2) + 4 * hi;
                    if (kloc > qloc) st[kf][reg] = -3.0e38f;
                }
        }

        // row max (lane-local + partner half)
        float tm = st[0][0];
        #pragma unroll
        for (int kf = 0; kf < 2; ++kf)
            #pragma unroll
            for (int reg = 0; reg < 16; ++reg) tm = fmaxf(tm, st[kf][reg]);
        tm = fmaxf(tm, __shfl_xor(tm, 32));

        // defer-max (raw threshold 64 = 8 in exp units)
        if (!__all(tm <= mreg + 64.f)) {
            const float mn = fmaxf(mreg, tm);
            const float sc = __expf((mreg - mn) * 0.125f);
            lreg *= sc;
            mreg = mn;
            #pragma unroll
            for (int reg = 0; reg < 16; ++reg) {
                const int qrow = (reg & 3) + 8 * (reg >> 2) + 4 * hi;
                const float scr = __shfl(sc, (lane & 32) | qrow);
                accO[0][reg] *= scr;
                accO[1][reg] *= scr;
            }
        }

        // p = exp(0.125*s - msc), in place; row sum
        const float msc = mreg * 0.125f;
        float rs = 0.f;
        #pragma unroll
        for (int kf = 0; kf < 2; ++kf)
            #pragma unroll
            for (int reg = 0; reg < 16; ++reg) {
                const float p = __expf(fmaf(st[kf][reg], 0.125f, -msc));
                st[kf][reg] = p;
                rs += p;
            }
        rs += __shfl_xor(rs, 32);
        lreg += rs;

        // pack P -> A-frags and accumulate PV
        #pragma unroll
        for (int ka = 0; ka < 4; ++ka) {
            const int kf = ka >> 1;
            const int rbS = 4 * (((ka & 1) << 1) + hi);
            const int rbO = 4 * (((ka & 1) << 1) + (hi ^ 1));
            const u32 a0 = pkpair(st[kf][rbS + 0], st[kf][rbS + 1]);
            const u32 a1 = pkpair(st[kf][rbS + 2], st[kf][rbS + 3]);
            const u32 b0 = pkpair(st[kf][rbO + 0], st[kf][rbO + 1]);
            const u32 b1 = pkpair(st[kf][rbO + 2], st[kf][rbO + 3]);
            const u32 r0 = __shfl_xor(b0, 32);
            const u32 r1 = __shfl_xor(b1, 32);
            union { u32 wd[4]; short8v v; } u;
            u.wd[0] = hi ? r0 : a0;
            u.wd[1] = hi ? r1 : a1;
            u.wd[2] = hi ? a0 : r0;
            u.wd[3] = hi ? a1 : r1;
            #pragma unroll
            for (int dc = 0; dc < 2; ++dc) {
                const short8v bv = *(const short8v*)(Vb +
                    SWZ(dc * 32 + l31, ka * 32 + hi * 16));
                accO[dc] = __builtin_amdgcn_mfma_f32_32x32x16_bf16(u.v, bv, accO[dc], 0, 0, 0);
            }
        }

        __syncthreads();   // drains next-tile GLLs; all waves done with buf[cur]
        cur ^= 1;
    }

    // epilogue: normalize rows, write ctx bf16 [b*t][768]
    const float inv = 1.f / lreg;
    const int qbase = qt * 64 + w * 32;
    #pragma unroll
    for (int reg = 0; reg < 16; ++reg) {
        const int qrow = (reg & 3) + 8 * (reg >> 2) + 4 * hi;
        const float invr = __shfl(inv, (lane & 32) | qrow);
        const int q = qbase + qrow;
        #pragma unroll
        for (int dc = 0; dc < 2; ++dc) {
            const int d = dc * 32 + l31;
            ctx[(size_t)(b * TT + q) * DD + h * 64 + d] = f2bf(accO[dc][reg] * invr);
        }
    }
#undef STAGE
}

extern "C" void kernel_launch(void* const* d_in, const int* in_sizes, int n_in,
                              void* d_out, int out_size, void* d_ws, size_t ws_size,
                              hipStream_t stream) {
    (void)in_sizes; (void)n_in; (void)out_size; (void)ws_size;
    const float* x  = (const float*)d_in[0];
    const float* Wq = (const float*)d_in[1];
    const float* bq = (const float*)d_in[2];
    const float* Wk = (const float*)d_in[3];
    const float* bk = (const float*)d_in[4];
    const float* Wv = (const float*)d_in[5];
    const float* bv = (const float*)d_in[6];
    const float* Wo = (const float*)d_in[7];
    const float* bo = (const float*)d_in[8];
    float* out = (float*)d_out;

    u16* xb    = (u16*)d_ws;
    u16* WtQ   = xb + (size_t)MM * DD;
    u16* WtK   = WtQ + (size_t)DD * DD;
    u16* WtV   = WtK + (size_t)DD * DD;
    u16* WtO   = WtV + (size_t)DD * DD;
    u16* qbuf  = WtO + (size_t)DD * DD;      // [b][h][t][d]
    u16* kbuf  = qbuf + (size_t)MM * DD;     // [b][h][t][d]
    u16* vtbuf = kbuf + (size_t)MM * DD;     // [b][h][d][t]
    u16* ctxb  = vtbuf + (size_t)MM * DD;    // [b*t][768]

    convert_x<<<3072, 256, 0, stream>>>(x, xb);
    transpose_cvt<<<dim3(12, 12, 4), 256, 0, stream>>>(Wq, Wk, Wv, Wo, WtQ, WtK, WtV, WtO);
    gemm_bt<<<dim3(32, 6, 3), 256, 0, stream>>>(xb, WtQ, WtK, WtV, bq, bk, bv,
                                                qbuf, kbuf, vtbuf, nullptr, 0);
    attn_fwd<<<dim3(768), 128, 0, stream>>>(qbuf, kbuf, vtbuf, ctxb);
    gemm_bt<<<dim3(32, 6, 1), 256, 0, stream>>>(ctxb, WtO, nullptr, nullptr, bo, nullptr, nullptr,
                                                nullptr, nullptr, nullptr, out, 3);
}

// Round 4
// 151.012 us; speedup vs baseline: 1.2049x; 1.2049x over previous
//
#include <hip/hip_runtime.h>
#include <hip/hip_bf16.h>
#include <math.h>

typedef unsigned short u16;
typedef unsigned int u32;
typedef __attribute__((ext_vector_type(8))) short short8v;   // 8 bf16 = 4 VGPR
typedef __attribute__((ext_vector_type(4))) float f32x4;
typedef __attribute__((ext_vector_type(16))) float f32x16;

#define BB 2
#define TT 2048
#define DD 768
#define HH 12
#define DHH 64
#define MM 4096   // BB*TT
#define NSLOT 80      // kv-split chunks per (bh): sum over qt of ceil((qt+1)/8)
#define C2 0.18033688f   // 0.125 * log2(e)

// XOR swizzle for the GEMM's row-major [r][128B] LDS tiles (read side).
#define SWZ(r, kb) (((r) * 128) + ((kb) ^ (((r) & 7) << 4)))

typedef __attribute__((address_space(1))) void gas_void;
typedef __attribute__((address_space(3))) void las_void;
#define GLL(g, l) __builtin_amdgcn_global_load_lds((gas_void*)(g), (las_void*)(l), 16, 0, 0)

__device__ __forceinline__ u16 f2bf(float f) {
    union { float f; unsigned u; } v; v.f = f;
    unsigned r = v.u + 0x7fff + ((v.u >> 16) & 1);   // RNE
    return (u16)(r >> 16);
}
__device__ __forceinline__ u32 pkpair(float a, float b) {   // low=a, high=b
    union { __hip_bfloat162 h; u32 u; } v;
    v.h = __float22bfloat162_rn(make_float2(a, b));
    return v.u;
}
__device__ __forceinline__ float fexp2(float x) {
#if __has_builtin(__builtin_amdgcn_exp2f)
    return __builtin_amdgcn_exp2f(x);
#else
    return exp2f(x);
#endif
}

// ---------------------------------------------------------------------------
// x fp32 -> bf16 row-major. grid 3072 x 256.
// ---------------------------------------------------------------------------
__global__ __launch_bounds__(256) void convert_x(const float* __restrict__ x,
                                                 u16* __restrict__ xb) {
    const int i = blockIdx.x * 256 + threadIdx.x;
    const float4 v = ((const float4*)x)[i];
    union { u16 s[4]; uint2 u; } o;
    o.s[0] = f2bf(v.x); o.s[1] = f2bf(v.y); o.s[2] = f2bf(v.z); o.s[3] = f2bf(v.w);
    ((uint2*)xb)[i] = o.u;
}

// ---------------------------------------------------------------------------
// W [K][N] fp32 -> Wt [N][K] bf16. grid (12,12,4).
// ---------------------------------------------------------------------------
__global__ __launch_bounds__(256) void transpose_cvt(
    const float* __restrict__ W0, const float* __restrict__ W1,
    const float* __restrict__ W2, const float* __restrict__ W3,
    u16* __restrict__ T0, u16* __restrict__ T1,
    u16* __restrict__ T2, u16* __restrict__ T3)
{
    const int z = blockIdx.z;
    const float* __restrict__ W = (z == 0) ? W0 : (z == 1) ? W1 : (z == 2) ? W2 : W3;
    u16* __restrict__ T = (z == 0) ? T0 : (z == 1) ? T1 : (z == 2) ? T2 : T3;

    __shared__ float tile[64][65];
    const int k0 = blockIdx.x * 64, n0 = blockIdx.y * 64;
    const int t = threadIdx.x;
    const int rr = t >> 4, c4 = (t & 15) * 4;

    #pragma unroll
    for (int j = 0; j < 4; ++j) {
        const int r = rr + j * 16;
        const float4 v = *(const float4*)&W[(size_t)(k0 + r) * DD + n0 + c4];
        tile[r][c4 + 0] = v.x; tile[r][c4 + 1] = v.y;
        tile[r][c4 + 2] = v.z; tile[r][c4 + 3] = v.w;
    }
    __syncthreads();
    #pragma unroll
    for (int j = 0; j < 4; ++j) {
        const int r = rr + j * 16;
        union { u16 s[4]; uint2 u; } o;
        #pragma unroll
        for (int jj = 0; jj < 4; ++jj) o.s[jj] = f2bf(tile[c4 + jj][r]);
        *(uint2*)&T[(size_t)(n0 + r) * DD + k0 + c4] = o.u;
    }
}

// ---------------------------------------------------------------------------
// bf16 MFMA GEMM, B^T input. 128x128, BK=64, 4 waves. GLL staging + SWZ reads.
// mode 0: Q row-major [bh][t][d]
// mode 1: K subtiled  [bh][kt][j=d>>3][krow=t&63][e=d&7]   (attn LDS image)
// mode 2: V subtiled  [bh][kt][j=(t>>3)&7][d][e=t&7]       (attn LDS image)
// mode 3: fp32 row-major d_out
// ---------------------------------------------------------------------------
__global__ __launch_bounds__(256) void gemm_bt(
    const u16* __restrict__ A,
    const u16* __restrict__ Bt0, const u16* __restrict__ Bt1, const u16* __restrict__ Bt2,
    const float* __restrict__ b0, const float* __restrict__ b1, const float* __restrict__ b2,
    u16* __restrict__ oQ, u16* __restrict__ oK, u16* __restrict__ oVt,
    float* __restrict__ oF, int mode_base)
{
    const int mode = mode_base + blockIdx.z;
    const u16* __restrict__ Bt = (mode == 1) ? Bt1 : (mode == 2) ? Bt2 : Bt0;
    const float* __restrict__ bias = (mode == 1) ? b1 : (mode == 2) ? b2 : b0;

    __shared__ __attribute__((aligned(16))) u16 As[128 * 64];
    __shared__ __attribute__((aligned(16))) u16 Bs[128 * 64];

    const int tid = threadIdx.x, lane = tid & 63, w = tid >> 6;
    const int wr = w >> 1, wc = w & 1;
    const int lr = lane >> 4, lc = lane & 15;
    const int m0 = blockIdx.x * 128, n0 = blockIdx.y * 128;
    const int srcoff = 16 * ((lane & 7) ^ (lane >> 3));   // inverse swizzle

    f32x4 acc[4][4];
    #pragma unroll
    for (int m = 0; m < 4; ++m)
        #pragma unroll
        for (int n = 0; n < 4; ++n) acc[m][n] = (f32x4){0.f, 0.f, 0.f, 0.f};

    #pragma unroll 1
    for (int k0 = 0; k0 < DD; k0 += 64) {
        __syncthreads();
        #pragma unroll
        for (int i = 0; i < 4; ++i) {
            const int r = w * 32 + i * 8 + (lane >> 3);
            GLL((const char*)A  + ((size_t)(m0 + r) * DD + k0) * 2 + srcoff,
                (char*)As + w * 4096 + i * 1024);
            GLL((const char*)Bt + ((size_t)(n0 + r) * DD + k0) * 2 + srcoff,
                (char*)Bs + w * 4096 + i * 1024);
        }
        __syncthreads();
        #pragma unroll
        for (int s = 0; s < 2; ++s) {
            short8v af[4], bf[4];
            #pragma unroll
            for (int m = 0; m < 4; ++m)
                af[m] = *(const short8v*)((const char*)As +
                         SWZ(wr * 64 + m * 16 + lc, s * 64 + lr * 16));
            #pragma unroll
            for (int n = 0; n < 4; ++n)
                bf[n] = *(const short8v*)((const char*)Bs +
                         SWZ(wc * 64 + n * 16 + lc, s * 64 + lr * 16));
            #pragma unroll
            for (int m = 0; m < 4; ++m)
                #pragma unroll
                for (int n = 0; n < 4; ++n)
                    acc[m][n] = __builtin_amdgcn_mfma_f32_16x16x32_bf16(
                        af[m], bf[n], acc[m][n], 0, 0, 0);
        }
    }

    #pragma unroll
    for (int n = 0; n < 4; ++n) {
        const int ng = n0 + wc * 64 + n * 16 + lc;
        const float bv = bias[ng];
        #pragma unroll
        for (int m = 0; m < 4; ++m) {
            const int mg0 = m0 + wr * 64 + m * 16 + lr * 4;
            if (mode == 3) {
                #pragma unroll
                for (int r = 0; r < 4; ++r)
                    oF[(size_t)(mg0 + r) * DD + ng] = acc[m][n][r] + bv;
            } else if (mode == 2) {
                // V subtiled: idx = bh*131072 + kt*4096 + j*512 + d*8 + e
                const int bb = mg0 >> 11, tp = mg0 & 2047;
                const int h = ng >> 6, d = ng & 63;
                const size_t idx = (size_t)(bb * HH + h) * (TT * DHH)
                                 + (tp >> 6) * 4096 + ((tp >> 3) & 7) * 512
                                 + d * 8 + (tp & 7);
                union { u16 s[4]; uint2 u; } o;
                #pragma unroll
                for (int r = 0; r < 4; ++r) o.s[r] = f2bf(acc[m][n][r] + bv);
                *(uint2*)&oVt[idx] = o.u;
            } else if (mode == 1) {
                // K subtiled: idx = bh*131072 + kt*4096 + (d>>3)*512 + krow*8 + (d&7)
                const int h = ng >> 6, d = ng & 63;
                #pragma unroll
                for (int r = 0; r < 4; ++r) {
                    const int mg = mg0 + r;
                    const int bb = mg >> 11, tp = mg & 2047;
                    oK[(size_t)(bb * HH + h) * (TT * DHH)
                       + (tp >> 6) * 4096 + (d >> 3) * 512 + (tp & 63) * 8 + (d & 7)] =
                        f2bf(acc[m][n][r] + bv);
                }
            } else {
                const int h = ng >> 6, d = ng & 63;
                #pragma unroll
                for (int r = 0; r < 4; ++r) {
                    const int mg = mg0 + r;
                    const int bb = mg >> 11, tp = mg & 2047;
                    oQ[((size_t)(bb * HH + h) * TT + tp) * DHH + d] =
                        f2bf(acc[m][n][r] + bv);
                }
            }
        }
    }
}

// ---------------------------------------------------------------------------
// KV-split MFMA flash attention partial. 32x32x16 swapped-QK^T core (proven
// in round 3). Each block: one (bh, qt64, chunk c) with kt in
// [c*8, min(c*8+8, qt+1)). 2 waves, wave w owns q rows qt*64+w*32..+31.
// K/V staged from their subtiled global images via fully-linear GLL,
// double-buffered; LDS reads are contiguous -> no bank conflicts, no swizzle.
// Partial (O, m, l) written to workspace; combine kernel merges chunks.
// grid = 1920 = 80 slots * 24 bh, heavy (high-qt) slots first,
// bid%24 = bh -> per-bh XCD affinity (24 = 0 mod 8).
// ---------------------------------------------------------------------------
__global__ __launch_bounds__(128) void attn_fwd(
    const u16* __restrict__ qb, const u16* __restrict__ kbf,
    const u16* __restrict__ vtb, float* __restrict__ partO,
    float* __restrict__ partML)
{
    __shared__ __attribute__((aligned(16))) unsigned char smem[32768];
    // K: buf0 @0, buf1 @8192 ; V: buf0 @16384, buf1 @24576

    const int bid = blockIdx.x;
    const int sp = bid / 24;
    const int bh = bid - sp * 24;
    const int s = (NSLOT - 1) - sp;        // slot within bh, heavy-first
    int qt, c;
    if (s < 8)       { qt = s;                              c = 0;          }
    else if (s < 24) { const int r = s - 8;  qt = 8  + (r >> 1); c = r & 1; }
    else if (s < 48) { const int r = s - 24; qt = 16 + r / 3;    c = r % 3; }
    else             { const int r = s - 48; qt = 24 + (r >> 2); c = r & 3; }
    const int kts = c * 8;
    const int kte = min(kts + 8, qt + 1);

    const int tid = threadIdx.x, lane = tid & 63, w = tid >> 6;
    const int l31 = lane & 31, hi = lane >> 5;
    const int lb16 = lane * 16;

    // Q fragments from global: Q[qt*64 + w*32 + l31][s4*16 + hi*8 .. +7]
    short8v aq[4];
    {
        const u16* qrow = qb + ((size_t)bh * TT + qt * 64 + w * 32 + l31) * DHH;
        #pragma unroll
        for (int s4 = 0; s4 < 4; ++s4)
            aq[s4] = *(const short8v*)(qrow + s4 * 16 + hi * 8);
    }

    const char* kbase = (const char*)kbf + (size_t)bh * (TT * DHH * 2);
    const char* vbase = (const char*)vtb + (size_t)bh * (TT * DHH * 2);

    // fully-linear staging of one 8KB K tile + 8KB V tile (4+4 GLL per wave)
#define STAGE(kt2, bufi) do {                                                  \
        const char* kb_ = kbase + (size_t)(kt2) * 8192;                        \
        const char* vb_ = vbase + (size_t)(kt2) * 8192;                        \
        _Pragma("unroll")                                                      \
        for (int i_ = 0; i_ < 4; ++i_) {                                       \
            const int j_ = w * 4 + i_;                                         \
            GLL(kb_ + j_ * 1024 + lb16,                                        \
                (char*)smem + (bufi) * 8192 + j_ * 1024);                      \
            GLL(vb_ + j_ * 1024 + lb16,                                        \
                (char*)smem + 16384 + (bufi) * 8192 + j_ * 1024);              \
        }                                                                      \
    } while (0)

    f32x16 accO[2];
    #pragma unroll
    for (int i = 0; i < 16; ++i) { accO[0][i] = 0.f; accO[1][i] = 0.f; }
    float mreg = -INFINITY, lreg = 0.f;

    STAGE(kts, 0);
    __syncthreads();

    int cur = 0;
    #pragma unroll 1
    for (int kt = kts; kt < kte; ++kt) {
        if (kt + 1 < kte) STAGE(kt + 1, cur ^ 1);

        const unsigned char* Kb = smem + cur * 8192;
        const unsigned char* Vb = smem + 16384 + cur * 8192;

        // S^T = K * Q^T (raw scores; scale folded into exp2)
        f32x16 st[2];
        #pragma unroll
        for (int i = 0; i < 16; ++i) { st[0][i] = 0.f; st[1][i] = 0.f; }
        #pragma unroll
        for (int s4 = 0; s4 < 4; ++s4) {
            #pragma unroll
            for (int kf = 0; kf < 2; ++kf) {
                const short8v ak = *(const short8v*)(Kb +
                    (s4 * 2 + hi) * 1024 + (kf * 32 + l31) * 16);
                st[kf] = __builtin_amdgcn_mfma_f32_32x32x16_bf16(ak, aq[s4], st[kf], 0, 0, 0);
            }
        }

        if (kt == qt) {   // causal mask on the diagonal tile
            const int qloc = w * 32 + l31;
            #pragma unroll
            for (int kf = 0; kf < 2; ++kf)
                #pragma unroll
                for (int reg = 0; reg < 16; ++reg) {
                    const int kloc = kf * 32 + (reg & 3) + 8 * (reg >> 2) + 4 * hi;
                    if (kloc > qloc) st[kf][reg] = -3.0e38f;
                }
        }

        // row max (lane-local + partner half)
        float tm = st[0][0];
        #pragma unroll
        for (int kf = 0; kf < 2; ++kf)
            #pragma unroll
            for (int reg = 0; reg < 16; ++reg) tm = fmaxf(tm, st[kf][reg]);
        tm = fmaxf(tm, __shfl_xor(tm, 32));

        // defer-max (raw threshold 64 = 8 in ln units)
        if (!__all(tm <= mreg + 64.f)) {
            const float mn = fmaxf(mreg, tm);
            const float sc = fexp2((mreg - mn) * C2);
            lreg *= sc;
            mreg = mn;
            #pragma unroll
            for (int reg = 0; reg < 16; ++reg) {
                const int qrow = (reg & 3) + 8 * (reg >> 2) + 4 * hi;
                const float scr = __shfl(sc, (lane & 32) | qrow);
                accO[0][reg] *= scr;
                accO[1][reg] *= scr;
            }
        }

        // p = exp2(s*C2 - mb); row sum
        const float mb = mreg * C2;
        float rs = 0.f;
        #pragma unroll
        for (int kf = 0; kf < 2; ++kf)
            #pragma unroll
            for (int reg = 0; reg < 16; ++reg) {
                const float p = fexp2(fmaf(st[kf][reg], C2, -mb));
                st[kf][reg] = p;
                rs += p;
            }
        rs += __shfl_xor(rs, 32);
        lreg += rs;

        // pack P -> A-frags, accumulate PV
        #pragma unroll
        for (int ka = 0; ka < 4; ++ka) {
            const int kf = ka >> 1;
            const int rbS = 4 * (((ka & 1) << 1) + hi);
            const int rbO = 4 * (((ka & 1) << 1) + (hi ^ 1));
            const u32 a0 = pkpair(st[kf][rbS + 0], st[kf][rbS + 1]);
            const u32 a1 = pkpair(st[kf][rbS + 2], st[kf][rbS + 3]);
            const u32 b0 = pkpair(st[kf][rbO + 0], st[kf][rbO + 1]);
            const u32 b1 = pkpair(st[kf][rbO + 2], st[kf][rbO + 3]);
            const u32 r0 = __shfl_xor(b0, 32);
            const u32 r1 = __shfl_xor(b1, 32);
            union { u32 wd[4]; short8v v; } u;
            u.wd[0] = hi ? r0 : a0;
            u.wd[1] = hi ? r1 : a1;
            u.wd[2] = hi ? a0 : r0;
            u.wd[3] = hi ? a1 : r1;
            #pragma unroll
            for (int dc = 0; dc < 2; ++dc) {
                const short8v bv = *(const short8v*)(Vb +
                    (ka * 2 + hi) * 1024 + (dc * 32 + l31) * 16);
                accO[dc] = __builtin_amdgcn_mfma_f32_32x32x16_bf16(u.v, bv, accO[dc], 0, 0, 0);
            }
        }

        __syncthreads();   // drains next-tile GLLs; all waves done with buf[cur]
        cur ^= 1;
    }

    // store partial (O, m, l). slot = bh*80 + s by construction.
    const int slot = bh * NSLOT + s;
    float* po = partO + (size_t)slot * 4096;
    if (hi == 0) {
        partML[(size_t)slot * 128 + w * 32 + l31] = mreg * C2;      // log2 units
        partML[(size_t)slot * 128 + 64 + w * 32 + l31] = lreg;
    }
    #pragma unroll
    for (int reg = 0; reg < 16; ++reg) {
        const int qrow = (reg & 3) + 8 * (reg >> 2) + 4 * hi;
        #pragma unroll
        for (int dc = 0; dc < 2; ++dc)
            po[(w * 32 + qrow) * 64 + dc * 32 + l31] = accO[dc][reg];
    }
#undef STAGE
}

// ---------------------------------------------------------------------------
// Merge KV-split partials, normalize, write ctx bf16 [b*t][768].
// grid = 768 (qt,bh), 256 threads: tid -> q = tid>>2 (64 rows), dg = tid&3.
// ---------------------------------------------------------------------------
__global__ __launch_bounds__(256) void attn_combine(
    const float* __restrict__ partO, const float* __restrict__ partML,
    u16* __restrict__ ctx)
{
    const int bid = blockIdx.x;
    const int qt = bid / 24, bh = bid - qt * 24;
    const int b = bh / HH, h = bh - b * HH;
    const int g = qt >> 3, nc = g + 1;
    const int slot0 = bh * NSLOT + 4 * g * (g + 1) + (qt & 7) * nc;
    const int tid = threadIdx.x, q = tid >> 2, dg = tid & 3;

    float mmax = -INFINITY;
    #pragma unroll 1
    for (int cc = 0; cc < nc; ++cc)
        mmax = fmaxf(mmax, partML[(size_t)(slot0 + cc) * 128 + q]);

    float lsum = 0.f;
    float4 a0 = make_float4(0,0,0,0), a1 = a0, a2 = a0, a3 = a0;
    #pragma unroll 1
    for (int cc = 0; cc < nc; ++cc) {
        const float wgt = fexp2(partML[(size_t)(slot0 + cc) * 128 + q] - mmax);
        lsum += wgt * partML[(size_t)(slot0 + cc) * 128 + 64 + q];
        const float* po = partO + (size_t)(slot0 + cc) * 4096 + q * 64 + dg * 16;
        const float4 o0 = *(const float4*)(po + 0);
        const float4 o1 = *(const float4*)(po + 4);
        const float4 o2 = *(const float4*)(po + 8);
        const float4 o3 = *(const float4*)(po + 12);
        a0.x += wgt*o0.x; a0.y += wgt*o0.y; a0.z += wgt*o0.z; a0.w += wgt*o0.w;
        a1.x += wgt*o1.x; a1.y += wgt*o1.y; a1.z += wgt*o1.z; a1.w += wgt*o1.w;
        a2.x += wgt*o2.x; a2.y += wgt*o2.y; a2.z += wgt*o2.z; a2.w += wgt*o2.w;
        a3.x += wgt*o3.x; a3.y += wgt*o3.y; a3.z += wgt*o3.z; a3.w += wgt*o3.w;
    }
    const float inv = 1.f / lsum;
    u16* dst = ctx + (size_t)(b * TT + qt * 64 + q) * DD + h * 64 + dg * 16;
    union { u16 s[4]; uint2 u; } o;
    o.s[0]=f2bf(a0.x*inv); o.s[1]=f2bf(a0.y*inv); o.s[2]=f2bf(a0.z*inv); o.s[3]=f2bf(a0.w*inv);
    *(uint2*)(dst + 0) = o.u;
    o.s[0]=f2bf(a1.x*inv); o.s[1]=f2bf(a1.y*inv); o.s[2]=f2bf(a1.z*inv); o.s[3]=f2bf(a1.w*inv);
    *(uint2*)(dst + 4) = o.u;
    o.s[0]=f2bf(a2.x*inv); o.s[1]=f2bf(a2.y*inv); o.s[2]=f2bf(a2.z*inv); o.s[3]=f2bf(a2.w*inv);
    *(uint2*)(dst + 8) = o.u;
    o.s[0]=f2bf(a3.x*inv); o.s[1]=f2bf(a3.y*inv); o.s[2]=f2bf(a3.z*inv); o.s[3]=f2bf(a3.w*inv);
    *(uint2*)(dst + 12) = o.u;
}

extern "C" void kernel_launch(void* const* d_in, const int* in_sizes, int n_in,
                              void* d_out, int out_size, void* d_ws, size_t ws_size,
                              hipStream_t stream) {
    (void)in_sizes; (void)n_in; (void)out_size; (void)ws_size;
    const float* x  = (const float*)d_in[0];
    const float* Wq = (const float*)d_in[1];
    const float* bq = (const float*)d_in[2];
    const float* Wk = (const float*)d_in[3];
    const float* bk = (const float*)d_in[4];
    const float* Wv = (const float*)d_in[5];
    const float* bv = (const float*)d_in[6];
    const float* Wo = (const float*)d_in[7];
    const float* bo = (const float*)d_in[8];
    float* out = (float*)d_out;

    u16* xb    = (u16*)d_ws;                 // 3.1M u16
    u16* WtQ   = xb + (size_t)MM * DD;
    u16* WtK   = WtQ + (size_t)DD * DD;
    u16* WtV   = WtK + (size_t)DD * DD;
    u16* WtO   = WtV + (size_t)DD * DD;
    u16* qbuf  = WtO + (size_t)DD * DD;      // [bh][t][d] row-major
    u16* kbuf  = qbuf + (size_t)MM * DD;     // [bh][kt][j][krow][e] subtiled
    u16* vtbuf = kbuf + (size_t)MM * DD;     // [bh][kt][j][d][e]   subtiled
    u16* ctxb  = vtbuf + (size_t)MM * DD;    // [b*t][768]
    float* pO  = (float*)(ctxb + (size_t)MM * DD);     // 1920 * 4096 f32
    float* pML = pO + (size_t)24 * NSLOT * 4096;       // 1920 * 128 f32

    convert_x<<<3072, 256, 0, stream>>>(x, xb);
    transpose_cvt<<<dim3(12, 12, 4), 256, 0, stream>>>(Wq, Wk, Wv, Wo, WtQ, WtK, WtV, WtO);
    gemm_bt<<<dim3(32, 6, 3), 256, 0, stream>>>(xb, WtQ, WtK, WtV, bq, bk, bv,
                                                qbuf, kbuf, vtbuf, nullptr, 0);
    attn_fwd<<<dim3(24 * NSLOT), 128, 0, stream>>>(qbuf, kbuf, vtbuf, pO, pML);
    attn_combine<<<dim3(768), 256, 0, stream>>>(pO, pML, ctxb);
    gemm_bt<<<dim3(32, 6, 1), 256, 0, stream>>>(ctxb, WtO, nullptr, nullptr, bo, nullptr, nullptr,
                                                nullptr, nullptr, nullptr, out, 3);
}

// Round 5
// 140.081 us; speedup vs baseline: 1.2989x; 1.0780x over previous
//
#include <hip/hip_runtime.h>
#include <hip/hip_bf16.h>
#include <math.h>

typedef unsigned short u16;
typedef unsigned int u32;
typedef __attribute__((ext_vector_type(8))) short short8v;   // 8 bf16 = 4 VGPR
typedef __attribute__((ext_vector_type(4))) float f32x4;
typedef __attribute__((ext_vector_type(16))) float f32x16;

#define BB 2
#define TT 2048
#define DD 768
#define HH 12
#define DHH 64
#define MM 4096      // BB*TT
#define NSLOT 40     // kv-split chunks per bh (128-row q blocks, 8-tile chunks)
#define QSC 0.18033688f   // 0.125 * log2(e): folded into Q at projection
#define THRL2 11.54f      // defer-max threshold, log2 units (= 8 nats)

// XOR swizzle for the GEMM's row-major [r][128B] LDS tiles (read side).
#define SWZ(r, kb) (((r) * 128) + ((kb) ^ (((r) & 7) << 4)))

typedef __attribute__((address_space(1))) void gas_void;
typedef __attribute__((address_space(3))) void las_void;
#define GLL(g, l) __builtin_amdgcn_global_load_lds((gas_void*)(g), (las_void*)(l), 16, 0, 0)

// LPT slot tables: chunk (qt,c); 8-tile chunks first, then 6,4,2.
__device__ const unsigned char SLOT_QT[40] = {
    15,15,15,15, 14,14,14, 13,13,13, 12,12,12, 11,11,11,
    10,10, 9,9, 8,8, 7,7, 6, 5, 4, 3,
    14,10,6,2, 13,9,5,1, 12,8,4,0};
__device__ const unsigned char SLOT_C[40] = {
    0,1,2,3, 0,1,2, 0,1,2, 0,1,2, 0,1,2,
    0,1, 0,1, 0,1, 0,1, 0, 0, 0, 0,
    3,2,1,0, 3,2,1,0, 3,2,1,0};
__device__ const unsigned char SLOT_OF[64] = {   // [qt*4 + c] -> slot
    39, 0, 0, 0,  35, 0, 0, 0,  31, 0, 0, 0,  27, 0, 0, 0,
    26,38, 0, 0,  25,34, 0, 0,  24,30, 0, 0,  22,23, 0, 0,
    20,21,37, 0,  18,19,33, 0,  16,17,29, 0,  13,14,15, 0,
    10,11,12,36,   7, 8, 9,32,   4, 5, 6,28,   0, 1, 2, 3};

__device__ __forceinline__ u16 f2bf(float f) {
    union { float f; unsigned u; } v; v.f = f;
    unsigned r = v.u + 0x7fff + ((v.u >> 16) & 1);   // RNE
    return (u16)(r >> 16);
}
__device__ __forceinline__ u32 pkpair(float a, float b) {   // low=a, high=b
    union { __hip_bfloat162 h; u32 u; } v;
    v.h = __float22bfloat162_rn(make_float2(a, b));
    return v.u;
}
__device__ __forceinline__ float fexp2(float x) {
#if __has_builtin(__builtin_amdgcn_exp2f)
    return __builtin_amdgcn_exp2f(x);
#else
    return exp2f(x);
#endif
}
__device__ __forceinline__ float bfhi(u32 p) {   // high bf16 of packed word
    union { u32 u; float f; } v; v.u = p & 0xffff0000u; return v.f;
}
__device__ __forceinline__ float bflo(u32 p) {   // low bf16
    union { u32 u; float f; } v; v.u = p << 16; return v.f;
}

// ---------------------------------------------------------------------------
// x fp32 -> bf16 row-major. grid 3072 x 256.
// ---------------------------------------------------------------------------
__global__ __launch_bounds__(256) void convert_x(const float* __restrict__ x,
                                                 u16* __restrict__ xb) {
    const int i = blockIdx.x * 256 + threadIdx.x;
    const float4 v = ((const float4*)x)[i];
    union { u16 s[4]; uint2 u; } o;
    o.s[0] = f2bf(v.x); o.s[1] = f2bf(v.y); o.s[2] = f2bf(v.z); o.s[3] = f2bf(v.w);
    ((uint2*)xb)[i] = o.u;
}

// ---------------------------------------------------------------------------
// W [K][N] fp32 -> Wt [N][K] bf16. grid (12,12,4).
// ---------------------------------------------------------------------------
__global__ __launch_bounds__(256) void transpose_cvt(
    const float* __restrict__ W0, const float* __restrict__ W1,
    const float* __restrict__ W2, const float* __restrict__ W3,
    u16* __restrict__ T0, u16* __restrict__ T1,
    u16* __restrict__ T2, u16* __restrict__ T3)
{
    const int z = blockIdx.z;
    const float* __restrict__ W = (z == 0) ? W0 : (z == 1) ? W1 : (z == 2) ? W2 : W3;
    u16* __restrict__ T = (z == 0) ? T0 : (z == 1) ? T1 : (z == 2) ? T2 : T3;

    __shared__ float tile[64][65];
    const int k0 = blockIdx.x * 64, n0 = blockIdx.y * 64;
    const int t = threadIdx.x;
    const int rr = t >> 4, c4 = (t & 15) * 4;

    #pragma unroll
    for (int j = 0; j < 4; ++j) {
        const int r = rr + j * 16;
        const float4 v = *(const float4*)&W[(size_t)(k0 + r) * DD + n0 + c4];
        tile[r][c4 + 0] = v.x; tile[r][c4 + 1] = v.y;
        tile[r][c4 + 2] = v.z; tile[r][c4 + 3] = v.w;
    }
    __syncthreads();
    #pragma unroll
    for (int j = 0; j < 4; ++j) {
        const int r = rr + j * 16;
        union { u16 s[4]; uint2 u; } o;
        #pragma unroll
        for (int jj = 0; jj < 4; ++jj) o.s[jj] = f2bf(tile[c4 + jj][r]);
        *(uint2*)&T[(size_t)(n0 + r) * DD + k0 + c4] = o.u;
    }
}

// ---------------------------------------------------------------------------
// bf16 MFMA GEMM, B^T input. 128x128, BK=64, 4 waves. GLL staging + SWZ reads.
// mode 0: Q row-major [bh][t][d], PRE-SCALED by QSC (softmax exp2 fold)
// mode 1: K subtiled  [bh][kt][j=d>>3][krow=t&63][e=d&7]   (attn LDS image)
// mode 2: V subtiled  [bh][kt][j=(t>>3)&7][d][e=t&7]       (attn LDS image)
// mode 3: fp32 row-major d_out
// ---------------------------------------------------------------------------
__global__ __launch_bounds__(256) void gemm_bt(
    const u16* __restrict__ A,
    const u16* __restrict__ Bt0, const u16* __restrict__ Bt1, const u16* __restrict__ Bt2,
    const float* __restrict__ b0, const float* __restrict__ b1, const float* __restrict__ b2,
    u16* __restrict__ oQ, u16* __restrict__ oK, u16* __restrict__ oVt,
    float* __restrict__ oF, int mode_base)
{
    const int mode = mode_base + blockIdx.z;
    const u16* __restrict__ Bt = (mode == 1) ? Bt1 : (mode == 2) ? Bt2 : Bt0;
    const float* __restrict__ bias = (mode == 1) ? b1 : (mode == 2) ? b2 : b0;

    __shared__ __attribute__((aligned(16))) u16 As[128 * 64];
    __shared__ __attribute__((aligned(16))) u16 Bs[128 * 64];

    const int tid = threadIdx.x, lane = tid & 63, w = tid >> 6;
    const int wr = w >> 1, wc = w & 1;
    const int lr = lane >> 4, lc = lane & 15;
    const int m0 = blockIdx.x * 128, n0 = blockIdx.y * 128;
    const int srcoff = 16 * ((lane & 7) ^ (lane >> 3));   // inverse swizzle

    f32x4 acc[4][4];
    #pragma unroll
    for (int m = 0; m < 4; ++m)
        #pragma unroll
        for (int n = 0; n < 4; ++n) acc[m][n] = (f32x4){0.f, 0.f, 0.f, 0.f};

    #pragma unroll 1
    for (int k0 = 0; k0 < DD; k0 += 64) {
        __syncthreads();
        #pragma unroll
        for (int i = 0; i < 4; ++i) {
            const int r = w * 32 + i * 8 + (lane >> 3);
            GLL((const char*)A  + ((size_t)(m0 + r) * DD + k0) * 2 + srcoff,
                (char*)As + w * 4096 + i * 1024);
            GLL((const char*)Bt + ((size_t)(n0 + r) * DD + k0) * 2 + srcoff,
                (char*)Bs + w * 4096 + i * 1024);
        }
        __syncthreads();
        #pragma unroll
        for (int s = 0; s < 2; ++s) {
            short8v af[4], bf[4];
            #pragma unroll
            for (int m = 0; m < 4; ++m)
                af[m] = *(const short8v*)((const char*)As +
                         SWZ(wr * 64 + m * 16 + lc, s * 64 + lr * 16));
            #pragma unroll
            for (int n = 0; n < 4; ++n)
                bf[n] = *(const short8v*)((const char*)Bs +
                         SWZ(wc * 64 + n * 16 + lc, s * 64 + lr * 16));
            #pragma unroll
            for (int m = 0; m < 4; ++m)
                #pragma unroll
                for (int n = 0; n < 4; ++n)
                    acc[m][n] = __builtin_amdgcn_mfma_f32_16x16x32_bf16(
                        af[m], bf[n], acc[m][n], 0, 0, 0);
        }
    }

    #pragma unroll
    for (int n = 0; n < 4; ++n) {
        const int ng = n0 + wc * 64 + n * 16 + lc;
        const float bv = bias[ng];
        #pragma unroll
        for (int m = 0; m < 4; ++m) {
            const int mg0 = m0 + wr * 64 + m * 16 + lr * 4;
            if (mode == 3) {
                #pragma unroll
                for (int r = 0; r < 4; ++r)
                    oF[(size_t)(mg0 + r) * DD + ng] = acc[m][n][r] + bv;
            } else if (mode == 2) {
                const int bb = mg0 >> 11, tp = mg0 & 2047;
                const int h = ng >> 6, d = ng & 63;
                const size_t idx = (size_t)(bb * HH + h) * (TT * DHH)
                                 + (tp >> 6) * 4096 + ((tp >> 3) & 7) * 512
                                 + d * 8 + (tp & 7);
                union { u16 s[4]; uint2 u; } o;
                #pragma unroll
                for (int r = 0; r < 4; ++r) o.s[r] = f2bf(acc[m][n][r] + bv);
                *(uint2*)&oVt[idx] = o.u;
            } else if (mode == 1) {
                const int h = ng >> 6, d = ng & 63;
                #pragma unroll
                for (int r = 0; r < 4; ++r) {
                    const int mg = mg0 + r;
                    const int bb = mg >> 11, tp = mg & 2047;
                    oK[(size_t)(bb * HH + h) * (TT * DHH)
                       + (tp >> 6) * 4096 + (d >> 3) * 512 + (tp & 63) * 8 + (d & 7)] =
                        f2bf(acc[m][n][r] + bv);
                }
            } else {
                const int h = ng >> 6, d = ng & 63;
                #pragma unroll
                for (int r = 0; r < 4; ++r) {
                    const int mg = mg0 + r;
                    const int bb = mg >> 11, tp = mg & 2047;
                    oQ[((size_t)(bb * HH + h) * TT + tp) * DHH + d] =
                        f2bf((acc[m][n][r] + bv) * QSC);
                }
            }
        }
    }
}

// ---------------------------------------------------------------------------
// KV-split MFMA flash attention partial. 32x32x16 swapped-QK^T core (bit-
// identical fragment mappings to the verified round-4 kernel).
// 4 waves/block, 128 q-rows/block (wave w owns rows qt*128+w*32..+31);
// chunks of <=8 kv tiles (64 keys each), K/V shared in LDS, double-buffered,
// fully-linear GLL staging from subtiled global images.
// grid = 960 = 40 LPT slots * 24 bh; bid%24 = bh -> per-bh XCD affinity.
// ---------------------------------------------------------------------------
__global__ __launch_bounds__(256) void attn_fwd(
    const u16* __restrict__ qb, const u16* __restrict__ kbf,
    const u16* __restrict__ vtb, u16* __restrict__ partO,
    float* __restrict__ partML)
{
    __shared__ __attribute__((aligned(16))) unsigned char smem[32768];
    // K: buf0 @0, buf1 @8192 ; V: buf0 @16384, buf1 @24576

    const int bid = blockIdx.x;
    const int sp = bid / 24;
    const int bh = bid - sp * 24;
    const int qt = SLOT_QT[sp], c = SLOT_C[sp];
    const int kts = c * 8;
    const int kte = min(kts + 8, 2 * qt + 2);

    const int tid = threadIdx.x, lane = tid & 63, w = tid >> 6;
    const int l31 = lane & 31, hi = lane >> 5;

    // Q fragments (pre-scaled at projection): row = qt*128 + w*32 + l31
    short8v aq[4];
    {
        const u16* qrow = qb + ((size_t)bh * TT + qt * 128 + w * 32 + l31) * DHH;
        #pragma unroll
        for (int s4 = 0; s4 < 4; ++s4)
            aq[s4] = *(const short8v*)(qrow + s4 * 16 + hi * 8);
    }

    const char* kbase = (const char*)kbf + (size_t)bh * (TT * DHH * 2);
    const char* vbase = (const char*)vtb + (size_t)bh * (TT * DHH * 2);

    // 16KB tile-pair staged by 4 waves: 2 K + 2 V GLLs per thread
#define STAGE(kt2, bufi) do {                                                  \
        const char* kb_ = kbase + (size_t)(kt2) * 8192;                        \
        const char* vb_ = vbase + (size_t)(kt2) * 8192;                        \
        _Pragma("unroll")                                                      \
        for (int i_ = 0; i_ < 2; ++i_) {                                       \
            const int off_ = i_ * 4096 + w * 1024;                             \
            GLL(kb_ + off_ + lane * 16,                                        \
                (char*)smem + (bufi) * 8192 + off_);                           \
            GLL(vb_ + off_ + lane * 16,                                        \
                (char*)smem + 16384 + (bufi) * 8192 + off_);                   \
        }                                                                      \
    } while (0)

    f32x16 accO[2];
    #pragma unroll
    for (int i = 0; i < 16; ++i) { accO[0][i] = 0.f; accO[1][i] = 0.f; }
    float mreg = -INFINITY, lreg = 0.f;

    STAGE(kts, 0);
    __syncthreads();

    int cur = 0;
    const int qmin = qt * 128 + w * 32;
    #pragma unroll 1
    for (int kt = kts; kt < kte; ++kt) {
        if (kt + 1 < kte) STAGE(kt + 1, cur ^ 1);

        if (kt * 64 <= qmin + 31) {   // wave has >=1 unmasked key in this tile
            const unsigned char* Kb = smem + cur * 8192;
            const unsigned char* Vb = smem + 16384 + cur * 8192;

            // S^T = K * Q^T (scores already in log2 units via Q prescale)
            f32x16 st[2];
            #pragma unroll
            for (int i = 0; i < 16; ++i) { st[0][i] = 0.f; st[1][i] = 0.f; }
            __builtin_amdgcn_s_setprio(1);
            #pragma unroll
            for (int s4 = 0; s4 < 4; ++s4) {
                #pragma unroll
                for (int kf = 0; kf < 2; ++kf) {
                    const short8v ak = *(const short8v*)(Kb +
                        (s4 * 2 + hi) * 1024 + (kf * 32 + l31) * 16);
                    st[kf] = __builtin_amdgcn_mfma_f32_32x32x16_bf16(ak, aq[s4], st[kf], 0, 0, 0);
                }
            }
            __builtin_amdgcn_s_setprio(0);

            if (kt * 64 + 63 > qmin) {   // partial-diagonal tile: mask
                const int rowrel = qmin + l31 - kt * 64;   // q col = l31
                #pragma unroll
                for (int kf = 0; kf < 2; ++kf)
                    #pragma unroll
                    for (int reg = 0; reg < 16; ++reg) {
                        const int kloc = kf * 32 + (reg & 3) + 8 * (reg >> 2) + 4 * hi;
                        if (kloc > rowrel) st[kf][reg] = -3.0e38f;
                    }
            }

            // row max (lane-local regs + partner half)
            float tm = st[0][0];
            #pragma unroll
            for (int kf = 0; kf < 2; ++kf)
                #pragma unroll
                for (int reg = 0; reg < 16; ++reg) tm = fmaxf(tm, st[kf][reg]);
            tm = fmaxf(tm, __shfl_xor(tm, 32));

            // defer-max
            if (!__all(tm <= mreg + THRL2)) {
                const float mn = fmaxf(mreg, tm);
                const float sc = fexp2(mreg - mn);
                lreg *= sc;
                mreg = mn;
                #pragma unroll
                for (int reg = 0; reg < 16; ++reg) {
                    const int qrow = (reg & 3) + 8 * (reg >> 2) + 4 * hi;
                    const float scr = __shfl(sc, (lane & 32) | qrow);
                    accO[0][reg] *= scr;
                    accO[1][reg] *= scr;
                }
            }

            // p = exp2(s - m); row sum
            float rs = 0.f;
            #pragma unroll
            for (int kf = 0; kf < 2; ++kf)
                #pragma unroll
                for (int reg = 0; reg < 16; ++reg) {
                    const float p = fexp2(st[kf][reg] - mreg);
                    st[kf][reg] = p;
                    rs += p;
                }
            rs += __shfl_xor(rs, 32);
            lreg += rs;

            // pack P -> A-frags, accumulate PV
            __builtin_amdgcn_s_setprio(1);
            #pragma unroll
            for (int ka = 0; ka < 4; ++ka) {
                const int kf = ka >> 1;
                const int rbS = 4 * (((ka & 1) << 1) + hi);
                const int rbO = 4 * (((ka & 1) << 1) + (hi ^ 1));
                const u32 a0 = pkpair(st[kf][rbS + 0], st[kf][rbS + 1]);
                const u32 a1 = pkpair(st[kf][rbS + 2], st[kf][rbS + 3]);
                const u32 b0 = pkpair(st[kf][rbO + 0], st[kf][rbO + 1]);
                const u32 b1 = pkpair(st[kf][rbO + 2], st[kf][rbO + 3]);
                const u32 r0 = __shfl_xor(b0, 32);
                const u32 r1 = __shfl_xor(b1, 32);
                union { u32 wd[4]; short8v v; } u;
                u.wd[0] = hi ? r0 : a0;
                u.wd[1] = hi ? r1 : a1;
                u.wd[2] = hi ? a0 : r0;
                u.wd[3] = hi ? a1 : r1;
                #pragma unroll
                for (int dc = 0; dc < 2; ++dc) {
                    const short8v bv = *(const short8v*)(Vb +
                        (ka * 2 + hi) * 1024 + (dc * 32 + l31) * 16);
                    accO[dc] = __builtin_amdgcn_mfma_f32_32x32x16_bf16(u.v, bv, accO[dc], 0, 0, 0);
                }
            }
            __builtin_amdgcn_s_setprio(0);
        }

        __syncthreads();   // drains next-tile GLLs; all waves done with buf[cur]
        cur ^= 1;
    }

    // store partials (O bf16, m/l f32)
    const int gslot = bh * NSLOT + sp;
    if (hi == 0) {
        partML[(size_t)gslot * 256 + w * 32 + l31] = mreg;          // log2 units
        partML[(size_t)gslot * 256 + 128 + w * 32 + l31] = lreg;
    }
    u16* po = partO + (size_t)gslot * 8192;
    #pragma unroll
    for (int reg = 0; reg < 16; ++reg) {
        const int qrow = (reg & 3) + 8 * (reg >> 2) + 4 * hi;
        #pragma unroll
        for (int dc = 0; dc < 2; ++dc)
            po[(w * 32 + qrow) * 64 + dc * 32 + l31] = f2bf(accO[dc][reg]);
    }
#undef STAGE
}

// ---------------------------------------------------------------------------
// Merge KV-split partials (<=4), normalize, write ctx bf16 [b*t][768].
// grid = 384 (qt128, bh); 256 thr: q = tid>>1 (128 rows), half = tid&1.
// ---------------------------------------------------------------------------
__global__ __launch_bounds__(256) void attn_combine(
    const u16* __restrict__ partO, const float* __restrict__ partML,
    u16* __restrict__ ctx)
{
    const int bid = blockIdx.x;
    const int qt = bid / 24, bh = bid - qt * 24;
    const int b = bh / HH, h = bh - b * HH;
    const int nc = (qt >> 2) + 1;
    const int tid = threadIdx.x, q = tid >> 1, half = tid & 1;

    const int g0 = bh * NSLOT + SLOT_OF[(qt << 2) + 0];
    const int g1 = (nc > 1) ? bh * NSLOT + SLOT_OF[(qt << 2) + 1] : g0;
    const int g2 = (nc > 2) ? bh * NSLOT + SLOT_OF[(qt << 2) + 2] : g0;
    const int g3 = (nc > 3) ? bh * NSLOT + SLOT_OF[(qt << 2) + 3] : g0;

    float m0 = partML[(size_t)g0 * 256 + q];
    float mmax = m0;
    float m1 = m0, m2 = m0, m3 = m0;
    if (nc > 1) { m1 = partML[(size_t)g1 * 256 + q]; mmax = fmaxf(mmax, m1); }
    if (nc > 2) { m2 = partML[(size_t)g2 * 256 + q]; mmax = fmaxf(mmax, m2); }
    if (nc > 3) { m3 = partML[(size_t)g3 * 256 + q]; mmax = fmaxf(mmax, m3); }

    float lsum = 0.f;
    float acc[32];
    #pragma unroll
    for (int j = 0; j < 32; ++j) acc[j] = 0.f;

#define ACCUM(gs, mval, pred) do {                                             \
        if (pred) {                                                            \
            const float wgt = fexp2((mval) - mmax);                            \
            lsum += wgt * partML[(size_t)(gs) * 256 + 128 + q];                \
            const u16* po_ = partO + (size_t)(gs) * 8192 + q * 64 + half * 32; \
            _Pragma("unroll")                                                  \
            for (int v_ = 0; v_ < 4; ++v_) {                                   \
                const uint4 pk = *(const uint4*)(po_ + v_ * 8);                \
                acc[v_*8+0] += wgt * bflo(pk.x); acc[v_*8+1] += wgt * bfhi(pk.x); \
                acc[v_*8+2] += wgt * bflo(pk.y); acc[v_*8+3] += wgt * bfhi(pk.y); \
                acc[v_*8+4] += wgt * bflo(pk.z); acc[v_*8+5] += wgt * bfhi(pk.z); \
                acc[v_*8+6] += wgt * bflo(pk.w); acc[v_*8+7] += wgt * bfhi(pk.w); \
            }                                                                  \
        }                                                                      \
    } while (0)

    ACCUM(g0, m0, true);
    ACCUM(g1, m1, nc > 1);
    ACCUM(g2, m2, nc > 2);
    ACCUM(g3, m3, nc > 3);
#undef ACCUM

    const float inv = 1.f / lsum;
    u16* dst = ctx + (size_t)(b * TT + qt * 128 + q) * DD + h * 64 + half * 32;
    #pragma unroll
    for (int v = 0; v < 4; ++v) {
        uint4 o;
        o.x = pkpair(acc[v*8+0] * inv, acc[v*8+1] * inv);
        o.y = pkpair(acc[v*8+2] * inv, acc[v*8+3] * inv);
        o.z = pkpair(acc[v*8+4] * inv, acc[v*8+5] * inv);
        o.w = pkpair(acc[v*8+6] * inv, acc[v*8+7] * inv);
        *(uint4*)(dst + v * 8) = o;
    }
}

extern "C" void kernel_launch(void* const* d_in, const int* in_sizes, int n_in,
                              void* d_out, int out_size, void* d_ws, size_t ws_size,
                              hipStream_t stream) {
    (void)in_sizes; (void)n_in; (void)out_size; (void)ws_size;
    const float* x  = (const float*)d_in[0];
    const float* Wq = (const float*)d_in[1];
    const float* bq = (const float*)d_in[2];
    const float* Wk = (const float*)d_in[3];
    const float* bk = (const float*)d_in[4];
    const float* Wv = (const float*)d_in[5];
    const float* bv = (const float*)d_in[6];
    const float* Wo = (const float*)d_in[7];
    const float* bo = (const float*)d_in[8];
    float* out = (float*)d_out;

    u16* xb    = (u16*)d_ws;
    u16* WtQ   = xb + (size_t)MM * DD;
    u16* WtK   = WtQ + (size_t)DD * DD;
    u16* WtV   = WtK + (size_t)DD * DD;
    u16* WtO   = WtV + (size_t)DD * DD;
    u16* qbuf  = WtO + (size_t)DD * DD;      // [bh][t][d] row-major, pre-scaled
    u16* kbuf  = qbuf + (size_t)MM * DD;     // [bh][kt][j][krow][e] subtiled
    u16* vtbuf = kbuf + (size_t)MM * DD;     // [bh][kt][j][d][e]   subtiled
    u16* ctxb  = vtbuf + (size_t)MM * DD;    // [b*t][768]
    u16* pO    = ctxb + (size_t)MM * DD;     // 960 slots * 8192 bf16
    float* pML = (float*)(pO + (size_t)24 * NSLOT * 8192);   // 960 * 256 f32

    convert_x<<<3072, 256, 0, stream>>>(x, xb);
    transpose_cvt<<<dim3(12, 12, 4), 256, 0, stream>>>(Wq, Wk, Wv, Wo, WtQ, WtK, WtV, WtO);
    gemm_bt<<<dim3(32, 6, 3), 256, 0, stream>>>(xb, WtQ, WtK, WtV, bq, bk, bv,
                                                qbuf, kbuf, vtbuf, nullptr, 0);
    attn_fwd<<<dim3(24 * NSLOT), 256, 0, stream>>>(qbuf, kbuf, vtbuf, pO, pML);
    attn_combine<<<dim3(384), 256, 0, stream>>>(pO, pML, ctxb);
    gemm_bt<<<dim3(32, 6, 1), 256, 0, stream>>>(ctxb, WtO, nullptr, nullptr, bo, nullptr, nullptr,
                                                nullptr, nullptr, nullptr, out, 3);
}